// Round 2
// baseline (1789.822 us; speedup 1.0000x reference)
//
#include <hip/hip_runtime.h>
#include <math.h>

// Problem: B=2, T=2048, D=1024, H=16, hd=64. fp32 in/out.
// Round 2: correct fp32 baseline (R1 had a compile error). GEMMs on vector ALU
// (no fp32 MFMA on CDNA4), flash-style causal attention (no SxS materialization).
// ws layout (floats): Q[4096*1024] K[..] V[..] Y[..] = 64 MB total.

#define Bsz  2
#define Tseq 2048
#define Dm   1024
#define NH   16
#define HD   64

// ------------------------- fp32 GEMM: C[M,N] = A[M,K] @ B[K,N] ----------------
// 64x64 tile, BK=16, 256 threads, 4x4 microtile per thread.
// LDS stride 68 floats: keeps float4 reads 16B-aligned and every access <=2-way
// bank aliasing (free per m136).
#define BM 64
#define BN 64
#define BK 16
#define LDS_S 68

__global__ __launch_bounds__(256) void gemm_f32(const float* __restrict__ A,
                                                const float* __restrict__ B,
                                                float* __restrict__ C,
                                                int M, int N, int K) {
    __shared__ float As[BK * LDS_S];  // As[k][m], m contiguous
    __shared__ float Bs[BK * LDS_S];  // Bs[k][n], n contiguous

    const int tid = threadIdx.x;
    const int tx = tid & 15;        // n-microtile
    const int ty = tid >> 4;        // m-microtile
    const int m0 = blockIdx.y * BM;
    const int n0 = blockIdx.x * BN;

    // staging thread mapping
    const int ak = tid & 15;        // k (fast, coalesced along A rows)
    const int am = tid >> 4;        // m base (0..15), +16*r
    const int bn = tid & 63;        // n (fast, coalesced along B rows)
    const int bk = tid >> 6;        // k base (0..3), +4*r

    float acc[4][4] = {};

    for (int k0 = 0; k0 < K; k0 += BK) {
        __syncthreads();  // protect previous iteration's LDS reads
#pragma unroll
        for (int r = 0; r < 4; ++r) {
            As[ak * LDS_S + am + 16 * r] = A[(m0 + am + 16 * r) * K + k0 + ak];
            Bs[(bk + 4 * r) * LDS_S + bn] = B[(k0 + bk + 4 * r) * N + n0 + bn];
        }
        __syncthreads();
#pragma unroll
        for (int kk = 0; kk < BK; ++kk) {
            const float4 av = *(const float4*)&As[kk * LDS_S + 4 * ty];
            const float4 bv = *(const float4*)&Bs[kk * LDS_S + 4 * tx];
            const float a_[4] = {av.x, av.y, av.z, av.w};
            const float b_[4] = {bv.x, bv.y, bv.z, bv.w};
#pragma unroll
            for (int i = 0; i < 4; ++i)
#pragma unroll
                for (int j = 0; j < 4; ++j)
                    acc[i][j] = fmaf(a_[i], b_[j], acc[i][j]);
        }
    }

#pragma unroll
    for (int i = 0; i < 4; ++i) {
        float4 cv = make_float4(acc[i][0], acc[i][1], acc[i][2], acc[i][3]);
        *(float4*)&C[(m0 + 4 * ty + i) * N + n0 + 4 * tx] = cv;
    }
}

// ------------------------- causal flash attention (fp32) ----------------------
// grid.x = B*H, grid.y = T/64. Block 256 = 4 waves; each wave owns 16 queries.
// lane = key index in dot phase; lane = dim index for O accumulator.
// P transposes lane=key -> lane=dim through a per-wave LDS buffer (m120 pattern;
// within-wave write->read needs only compiler-inserted lgkmcnt, no barrier).
#define QT  64
#define KT  64
#define QPW 16

__global__ __launch_bounds__(256) void attn_f32(const float* __restrict__ Q,
                                                const float* __restrict__ K,
                                                const float* __restrict__ V,
                                                float* __restrict__ Y) {
    const int bh = blockIdx.x;
    const int b = bh / NH, h = bh % NH;
    const int t0 = blockIdx.y * QT;
    const int tid = threadIdx.x;
    const int lane = tid & 63;
    const int wave = tid >> 6;
    const int row0 = b * Tseq;
    const int colh = h * HD;

    __shared__ float Qs[QT][HD];        // broadcast reads only
    __shared__ float Ks[KT][HD + 1];    // [key][d], stride 65 -> <=2-way
    __shared__ float Vs[KT][HD + 1];    // [key][d]
    __shared__ float Ps[4][QPW][HD];    // per-wave p transpose buffer

    const float scale = 0.125f;  // 1/sqrt(64)
#pragma unroll
    for (int r = 0; r < (QT * HD) / 256; ++r) {
        int idx = r * 256 + tid;
        int q = idx >> 6, d = idx & 63;
        Qs[q][d] = Q[(row0 + t0 + q) * Dm + colh + d] * scale;
    }

    float m_i[QPW], l_i[QPW], o_i[QPW];
#pragma unroll
    for (int i = 0; i < QPW; ++i) { m_i[i] = -1e30f; l_i[i] = 0.f; o_i[i] = 0.f; }

    const int qw0 = t0 + wave * QPW;       // wave's first query (global token)
    const int qwmax = qw0 + QPW - 1;
    const int nkt = blockIdx.y + 1;        // causal: tiles 0..blockIdx.y

    for (int kt = 0; kt < nkt; ++kt) {
        const int k0 = kt * KT;
        __syncthreads();
#pragma unroll
        for (int r = 0; r < (KT * HD) / 256; ++r) {
            int idx = r * 256 + tid;
            int kk = idx >> 6, d = idx & 63;
            Ks[kk][d] = K[(row0 + k0 + kk) * Dm + colh + d];
            Vs[kk][d] = V[(row0 + k0 + kk) * Dm + colh + d];
        }
        __syncthreads();
        if (k0 > qwmax) continue;  // wave-uniform; both barriers already passed

        // ---- dot phase: s[i] = q_i . k_lane
        float s[QPW];
#pragma unroll
        for (int i = 0; i < QPW; ++i) s[i] = 0.f;
#pragma unroll
        for (int c = 0; c < 4; ++c) {
            float kreg[16];
#pragma unroll
            for (int j = 0; j < 16; ++j) kreg[j] = Ks[lane][c * 16 + j];
#pragma unroll
            for (int i = 0; i < QPW; ++i) {
#pragma unroll
                for (int j = 0; j < 16; ++j)
                    s[i] = fmaf(Qs[wave * QPW + i][c * 16 + j], kreg[j], s[i]);
            }
        }

        // ---- online softmax per query (lane = key)
        const int kglob = k0 + lane;
#pragma unroll
        for (int i = 0; i < QPW; ++i) {
            const int qglob = qw0 + i;
            float si = (kglob <= qglob) ? s[i] : -1e30f;
            float mx = si;
#pragma unroll
            for (int off = 32; off; off >>= 1) mx = fmaxf(mx, __shfl_xor(mx, off));
            const float mnew = fmaxf(m_i[i], mx);
            const float p = __expf(si - mnew);
            float sum = p;
#pragma unroll
            for (int off = 32; off; off >>= 1) sum += __shfl_xor(sum, off);
            const float alpha = __expf(m_i[i] - mnew);
            l_i[i] = l_i[i] * alpha + sum;
            m_i[i] = mnew;
            o_i[i] *= alpha;
            Ps[wave][i][lane] = p;
        }

        // ---- PV phase: o[i][lane=d] += sum_k p[i][k] * V[k][d]
#pragma unroll
        for (int c = 0; c < 4; ++c) {
            float vreg[16];
#pragma unroll
            for (int j = 0; j < 16; ++j) vreg[j] = Vs[c * 16 + j][lane];
#pragma unroll
            for (int i = 0; i < QPW; ++i) {
                float acc = 0.f;
#pragma unroll
                for (int j = 0; j < 16; ++j)
                    acc = fmaf(Ps[wave][i][c * 16 + j], vreg[j], acc);
                o_i[i] += acc;
            }
        }
    }

#pragma unroll
    for (int i = 0; i < QPW; ++i) {
        const int q = qw0 + i;
        Y[(row0 + q) * Dm + colh + lane] = o_i[i] / l_i[i];
    }
}

// ------------------------------- launch --------------------------------------
extern "C" void kernel_launch(void* const* d_in, const int* in_sizes, int n_in,
                              void* d_out, int out_size, void* d_ws, size_t ws_size,
                              hipStream_t stream) {
    const float* x  = (const float*)d_in[0];
    const float* Wq = (const float*)d_in[1];
    const float* Wk = (const float*)d_in[2];
    const float* Wv = (const float*)d_in[3];
    const float* Wo = (const float*)d_in[4];
    float* out = (float*)d_out;

    const int M = Bsz * Tseq;                 // 4096
    float* ws = (float*)d_ws;
    float* Qp = ws;
    float* Kp = ws + (size_t)M * Dm;
    float* Vp = ws + 2 * (size_t)M * Dm;
    float* Yp = ws + 3 * (size_t)M * Dm;      // needs 64 MB of ws

    dim3 blk(256);
    dim3 ggrid(Dm / BN, M / BM);              // (16, 64)
    hipLaunchKernelGGL(gemm_f32, ggrid, blk, 0, stream, x, Wq, Qp, M, Dm, Dm);
    hipLaunchKernelGGL(gemm_f32, ggrid, blk, 0, stream, x, Wk, Kp, M, Dm, Dm);
    hipLaunchKernelGGL(gemm_f32, ggrid, blk, 0, stream, x, Wv, Vp, M, Dm, Dm);

    dim3 agrid(Bsz * NH, Tseq / QT);          // (32, 32)
    hipLaunchKernelGGL(attn_f32, agrid, blk, 0, stream, Qp, Kp, Vp, Yp);

    hipLaunchKernelGGL(gemm_f32, ggrid, blk, 0, stream, Yp, Wo, out, M, Dm, Dm);
}

// Round 4
// 676.449 us; speedup vs baseline: 2.6459x; 2.6459x over previous
//
#include <hip/hip_runtime.h>
#include <hip/hip_bf16.h>
#include <math.h>

// B=2, T=2048, D=1024, H=16, hd=64. fp32 in/out.
// Round 4: attention -> bf16 MFMA flash kernel (R3 + pointer-arith paren fix).
// GEMMs still fp32 vector ALU (ported next round); Q/K GEMMs emit bf16
// directly (Q pre-scaled 1/8).
// ws layout (bytes): Qb[8M] Kb[8M] VbT[8M] Vp[16M] Yp[16M] = 56 MB.

#define Bsz  2
#define Tseq 2048
#define Dm   1024
#define NH   16
#define HD   64

typedef short bf16x8 __attribute__((ext_vector_type(8)));
typedef float floatx4 __attribute__((ext_vector_type(4)));

__device__ __forceinline__ unsigned short f2bf(float f) {
    __hip_bfloat16 h = __float2bfloat16(f);
    return *reinterpret_cast<unsigned short*>(&h);
}

// ------------------------- fp32 GEMM: C[M,N] = A[M,K] @ B[K,N] ----------------
#define BM 64
#define BN 64
#define BK 16
#define LDS_S 68

__global__ __launch_bounds__(256) void gemm_f32(const float* __restrict__ A,
                                                const float* __restrict__ B,
                                                float* __restrict__ C,
                                                int M, int N, int K) {
    __shared__ float As[BK * LDS_S];
    __shared__ float Bs[BK * LDS_S];
    const int tid = threadIdx.x;
    const int tx = tid & 15, ty = tid >> 4;
    const int m0 = blockIdx.y * BM, n0 = blockIdx.x * BN;
    const int ak = tid & 15, am = tid >> 4;
    const int bn = tid & 63, bk = tid >> 6;
    float acc[4][4] = {};
    for (int k0 = 0; k0 < K; k0 += BK) {
        __syncthreads();
#pragma unroll
        for (int r = 0; r < 4; ++r) {
            As[ak * LDS_S + am + 16 * r] = A[(m0 + am + 16 * r) * K + k0 + ak];
            Bs[(bk + 4 * r) * LDS_S + bn] = B[(k0 + bk + 4 * r) * N + n0 + bn];
        }
        __syncthreads();
#pragma unroll
        for (int kk = 0; kk < BK; ++kk) {
            const float4 av = *(const float4*)&As[kk * LDS_S + 4 * ty];
            const float4 bv = *(const float4*)&Bs[kk * LDS_S + 4 * tx];
            const float a_[4] = {av.x, av.y, av.z, av.w};
            const float b_[4] = {bv.x, bv.y, bv.z, bv.w};
#pragma unroll
            for (int i = 0; i < 4; ++i)
#pragma unroll
                for (int j = 0; j < 4; ++j)
                    acc[i][j] = fmaf(a_[i], b_[j], acc[i][j]);
        }
    }
#pragma unroll
    for (int i = 0; i < 4; ++i) {
        float4 cv = make_float4(acc[i][0], acc[i][1], acc[i][2], acc[i][3]);
        *(float4*)&C[(m0 + 4 * ty + i) * N + n0 + 4 * tx] = cv;
    }
}

// Same GEMM but bf16 output with fused scale (for Q and K projections).
__global__ __launch_bounds__(256) void gemm_bf16out(const float* __restrict__ A,
                                                    const float* __restrict__ B,
                                                    unsigned short* __restrict__ C,
                                                    int M, int N, int K, float scale) {
    __shared__ float As[BK * LDS_S];
    __shared__ float Bs[BK * LDS_S];
    const int tid = threadIdx.x;
    const int tx = tid & 15, ty = tid >> 4;
    const int m0 = blockIdx.y * BM, n0 = blockIdx.x * BN;
    const int ak = tid & 15, am = tid >> 4;
    const int bn = tid & 63, bk = tid >> 6;
    float acc[4][4] = {};
    for (int k0 = 0; k0 < K; k0 += BK) {
        __syncthreads();
#pragma unroll
        for (int r = 0; r < 4; ++r) {
            As[ak * LDS_S + am + 16 * r] = A[(m0 + am + 16 * r) * K + k0 + ak];
            Bs[(bk + 4 * r) * LDS_S + bn] = B[(k0 + bk + 4 * r) * N + n0 + bn];
        }
        __syncthreads();
#pragma unroll
        for (int kk = 0; kk < BK; ++kk) {
            const float4 av = *(const float4*)&As[kk * LDS_S + 4 * ty];
            const float4 bv = *(const float4*)&Bs[kk * LDS_S + 4 * tx];
            const float a_[4] = {av.x, av.y, av.z, av.w};
            const float b_[4] = {bv.x, bv.y, bv.z, bv.w};
#pragma unroll
            for (int i = 0; i < 4; ++i)
#pragma unroll
                for (int j = 0; j < 4; ++j)
                    acc[i][j] = fmaf(a_[i], b_[j], acc[i][j]);
        }
    }
#pragma unroll
    for (int i = 0; i < 4; ++i) {
        ushort4 ov;
        ov.x = f2bf(acc[i][0] * scale);
        ov.y = f2bf(acc[i][1] * scale);
        ov.z = f2bf(acc[i][2] * scale);
        ov.w = f2bf(acc[i][3] * scale);
        *(ushort4*)&C[(size_t)(m0 + 4 * ty + i) * N + n0 + 4 * tx] = ov;
    }
}

// ---------------- V transpose+cast: Vp fp32 [tok][Dm] -> VbT bf16 [bh][d][T] --
__global__ __launch_bounds__(256) void vtrans(const float* __restrict__ Vp,
                                              unsigned short* __restrict__ VbT) {
    __shared__ float tile[64][65];
    const int tt = blockIdx.x;   // token tile (64 global tokens)
    const int h = blockIdx.y;
    const int tid = threadIdx.x;
    const int row = tid >> 6;    // 0..3
    const int col = tid & 63;
#pragma unroll
    for (int p = 0; p < 16; ++p) {
        int i = p * 4 + row;
        tile[i][col] = Vp[(size_t)(tt * 64 + i) * Dm + h * HD + col];
    }
    __syncthreads();
    const int gt0 = tt * 64;
    const int b = gt0 / Tseq;
    const int lt0 = gt0 - b * Tseq;
#pragma unroll
    for (int p = 0; p < 16; ++p) {
        int d = p * 4 + row;
        VbT[((size_t)(b * NH + h) * HD + d) * Tseq + lt0 + col] = f2bf(tile[col][d]);
    }
}

// ------------------------- bf16 MFMA causal flash attention -------------------
// grid (B*NH=32, 16). Block = 4 waves; each block does q-tile pair {y, 31-y}
// (33 K-tiles each -> perfectly balanced). Wave owns 16 queries.
// Layouts (16x16x32 bf16 MFMA): C/D col=lane&15 row=quad*4+reg;
// A[m=lane&15][k=quad*8+j]; B[k=quad*8+j][n=lane&15].
__global__ __launch_bounds__(256) void attn_mfma(const unsigned short* __restrict__ Qb,
                                                 const unsigned short* __restrict__ Kb,
                                                 const unsigned short* __restrict__ VbT,
                                                 float* __restrict__ Y) {
    const int bh = blockIdx.x;
    const int b = bh >> 4;
    const int h = bh & 15;
    const int ypair = blockIdx.y;
    const int tid = threadIdx.x;
    const int wave = tid >> 6;
    const int lane = tid & 63;
    const int l15 = lane & 15;
    const int quad = lane >> 4;

    __shared__ unsigned short Ks[64][72];      // [key][d]
    __shared__ unsigned short Vt[64][72];      // [d][key]
    __shared__ unsigned short Ps[4][16][72];   // per-wave P transpose buffer

    const size_t tok0 = (size_t)b * Tseq;
    const int colh = h * HD;
    const unsigned short* vbase = VbT + (size_t)bh * HD * Tseq;

    // staging: 32 threads per row, uint = 2 bf16
    const int srow = tid >> 5;    // 0..7
    const int scol2 = tid & 31;   // uint column

    for (int phase = 0; phase < 2; ++phase) {
        const int qt = (phase == 0) ? ypair : (31 - ypair);
        const int qrow = qt * 64 + wave * 16;   // within-batch query base for wave

        // hoist Q A-fragments from global (loop-invariant)
        const unsigned short* qptr = Qb + (tok0 + qrow + l15) * Dm + colh + quad * 8;
        const bf16x8 qf0 = *(const bf16x8*)(qptr);
        const bf16x8 qf1 = *(const bf16x8*)(qptr + 32);

        float m_r[4], l_r[4];
        floatx4 o_acc[4];
#pragma unroll
        for (int r = 0; r < 4; ++r) { m_r[r] = -3.0e38f; l_r[r] = 0.f; }
#pragma unroll
        for (int t = 0; t < 4; ++t) o_acc[t] = (floatx4){0.f, 0.f, 0.f, 0.f};

        for (int kt = 0; kt <= qt; ++kt) {
            const int k0 = kt * 64;
            __syncthreads();
#pragma unroll
            for (int p = 0; p < 8; ++p) {
                const int rr = p * 8 + srow;   // key for Ks, dim for Vt
                *(unsigned int*)&Ks[rr][scol2 * 2] =
                    *(const unsigned int*)(Kb + (tok0 + k0 + rr) * Dm + colh + scol2 * 2);
                *(unsigned int*)&Vt[rr][scol2 * 2] =
                    *(const unsigned int*)(vbase + (size_t)rr * Tseq + k0 + scol2 * 2);
            }
            __syncthreads();

            // ---- QK^T: S (16 x 64) as 4 C-frags
            floatx4 s[4];
#pragma unroll
            for (int t = 0; t < 4; ++t) {
                floatx4 c = (floatx4){0.f, 0.f, 0.f, 0.f};
                const bf16x8 b0 = *(const bf16x8*)&Ks[t * 16 + l15][quad * 8];
                const bf16x8 b1 = *(const bf16x8*)&Ks[t * 16 + l15][32 + quad * 8];
                c = __builtin_amdgcn_mfma_f32_16x16x32_bf16(qf0, b0, c, 0, 0, 0);
                c = __builtin_amdgcn_mfma_f32_16x16x32_bf16(qf1, b1, c, 0, 0, 0);
                s[t] = c;
            }

            // ---- causal mask (diagonal tile only)
            if (kt == qt) {
#pragma unroll
                for (int t = 0; t < 4; ++t)
#pragma unroll
                    for (int r = 0; r < 4; ++r) {
                        const int kl = t * 16 + l15;
                        const int ql = wave * 16 + quad * 4 + r;
                        if (kl > ql) s[t][r] = -3.0e38f;
                    }
            }

            // ---- online softmax (rows = quad*4+r, cols across 16 lanes of quad)
            float rm[4];
#pragma unroll
            for (int r = 0; r < 4; ++r)
                rm[r] = fmaxf(fmaxf(s[0][r], s[1][r]), fmaxf(s[2][r], s[3][r]));
#pragma unroll
            for (int off = 1; off < 16; off <<= 1)
#pragma unroll
                for (int r = 0; r < 4; ++r)
                    rm[r] = fmaxf(rm[r], __shfl_xor(rm[r], off));
            float alpha[4];
#pragma unroll
            for (int r = 0; r < 4; ++r) {
                const float mn = fmaxf(m_r[r], rm[r]);
                alpha[r] = __expf(m_r[r] - mn);
                m_r[r] = mn;
            }
            float rs[4] = {0.f, 0.f, 0.f, 0.f};
#pragma unroll
            for (int t = 0; t < 4; ++t)
#pragma unroll
                for (int r = 0; r < 4; ++r) {
                    const float p = __expf(s[t][r] - m_r[r]);
                    rs[r] += p;
                    Ps[wave][quad * 4 + r][t * 16 + l15] = f2bf(p);
                }
#pragma unroll
            for (int off = 1; off < 16; off <<= 1)
#pragma unroll
                for (int r = 0; r < 4; ++r)
                    rs[r] += __shfl_xor(rs[r], off);
#pragma unroll
            for (int r = 0; r < 4; ++r)
                l_r[r] = l_r[r] * alpha[r] + rs[r];
#pragma unroll
            for (int t = 0; t < 4; ++t)
#pragma unroll
                for (int r = 0; r < 4; ++r)
                    o_acc[t][r] *= alpha[r];

            // ---- PV: O (16 x 64) += P (16 x 64) @ V (64 x 64)
            // (per-wave LDS round-trip; within-wave dep -> compiler lgkmcnt)
            const bf16x8 pa0 = *(const bf16x8*)&Ps[wave][l15][quad * 8];
            const bf16x8 pa1 = *(const bf16x8*)&Ps[wave][l15][32 + quad * 8];
#pragma unroll
            for (int t = 0; t < 4; ++t) {
                const bf16x8 vb0 = *(const bf16x8*)&Vt[t * 16 + l15][quad * 8];
                const bf16x8 vb1 = *(const bf16x8*)&Vt[t * 16 + l15][32 + quad * 8];
                o_acc[t] = __builtin_amdgcn_mfma_f32_16x16x32_bf16(pa0, vb0, o_acc[t], 0, 0, 0);
                o_acc[t] = __builtin_amdgcn_mfma_f32_16x16x32_bf16(pa1, vb1, o_acc[t], 0, 0, 0);
            }
        }

        // ---- epilogue: Y[q][colh + dim] = O / l
#pragma unroll
        for (int t = 0; t < 4; ++t)
#pragma unroll
            for (int r = 0; r < 4; ++r) {
                const int q = qrow + quad * 4 + r;
                Y[(tok0 + q) * Dm + colh + t * 16 + l15] = o_acc[t][r] / l_r[r];
            }
    }
}

// ------------------------------- launch --------------------------------------
extern "C" void kernel_launch(void* const* d_in, const int* in_sizes, int n_in,
                              void* d_out, int out_size, void* d_ws, size_t ws_size,
                              hipStream_t stream) {
    const float* x  = (const float*)d_in[0];
    const float* Wq = (const float*)d_in[1];
    const float* Wk = (const float*)d_in[2];
    const float* Wv = (const float*)d_in[3];
    const float* Wo = (const float*)d_in[4];
    float* out = (float*)d_out;

    const int M = Bsz * Tseq;  // 4096
    char* ws = (char*)d_ws;
    unsigned short* Qb  = (unsigned short*)(ws);                          // 8 MB
    unsigned short* Kb  = (unsigned short*)(ws + (((size_t)8)  << 20));   // 8 MB
    unsigned short* VbT = (unsigned short*)(ws + (((size_t)16) << 20));   // 8 MB
    float*          Vp  = (float*)         (ws + (((size_t)24) << 20));   // 16 MB
    float*          Yp  = (float*)         (ws + (((size_t)40) << 20));   // 16 MB

    dim3 blk(256);
    dim3 ggrid(Dm / BN, M / BM);  // (16, 64)
    hipLaunchKernelGGL(gemm_bf16out, ggrid, blk, 0, stream, x, Wq, Qb, M, Dm, Dm, 0.125f);
    hipLaunchKernelGGL(gemm_bf16out, ggrid, blk, 0, stream, x, Wk, Kb, M, Dm, Dm, 1.0f);
    hipLaunchKernelGGL(gemm_f32,     ggrid, blk, 0, stream, x, Wv, Vp, M, Dm, Dm);

    hipLaunchKernelGGL(vtrans, dim3(M / 64, NH), blk, 0, stream, Vp, VbT);

    hipLaunchKernelGGL(attn_mfma, dim3(Bsz * NH, 16), blk, 0, stream, Qb, Kb, VbT, Yp);

    hipLaunchKernelGGL(gemm_f32, ggrid, blk, 0, stream, Yp, Wo, out, M, Dm, Dm);
}

// Round 5
// 220.802 us; speedup vs baseline: 8.1060x; 3.0636x over previous
//
#include <hip/hip_runtime.h>
#include <hip/hip_bf16.h>
#include <math.h>

// B=2, T=2048, D=1024, H=16, hd=64. fp32 in/out.
// Round 5: all GEMMs -> bf16 MFMA (m97 structure: 128x128 tile, BK=32,
// global_load_lds width=16, unpadded LDS, B^T staging). QKV fused in one
// launch (grid.z) for 3 blocks/CU. Attention kernel unchanged except bf16
// Y output. ws (MB): xb@0[8] Wqt@8[2] Wkt@10[2] Wvt@12[2] Wot@14[2]
// Qb@16[8] Kb@24[8] Vb@32[8] VbT@40[8] Yb@48[8] = 56 MB.

#define Bsz  2
#define Tseq 2048
#define Dm   1024
#define NH   16
#define HD   64

typedef short bf16x8 __attribute__((ext_vector_type(8)));
typedef float floatx4 __attribute__((ext_vector_type(4)));

__device__ __forceinline__ unsigned short f2bf(float f) {
    __hip_bfloat16 h = __float2bfloat16(f);
    return *reinterpret_cast<unsigned short*>(&h);
}

// async global->LDS, 16 B per lane. LDS dest must be waveBase + lane*16.
__device__ __forceinline__ void lds16(unsigned short* lds, const unsigned short* g) {
    __builtin_amdgcn_global_load_lds(
        (const __attribute__((address_space(1))) void*)g,
        (__attribute__((address_space(3))) void*)lds, 16, 0, 0);
}

// ---------------- cast x fp32 -> bf16 ----------------------------------------
__global__ __launch_bounds__(256) void cast_x(const float* __restrict__ x,
                                              unsigned short* __restrict__ xb) {
    const size_t i = (size_t)blockIdx.x * 256 + threadIdx.x;
    const float4 v = ((const float4*)x)[i];
    ushort4 o;
    o.x = f2bf(v.x); o.y = f2bf(v.y); o.z = f2bf(v.z); o.w = f2bf(v.w);
    ((ushort4*)xb)[i] = o;
}

// ---------------- W fp32 [k][n] -> Wt bf16 [n][k] ----------------------------
__global__ __launch_bounds__(256) void wtrans(const float* __restrict__ W0,
                                              const float* __restrict__ W1,
                                              const float* __restrict__ W2,
                                              const float* __restrict__ W3,
                                              unsigned short* __restrict__ T0,
                                              unsigned short* __restrict__ T1,
                                              unsigned short* __restrict__ T2,
                                              unsigned short* __restrict__ T3) {
    const int z = blockIdx.z;
    const float* W = (z == 0) ? W0 : (z == 1) ? W1 : (z == 2) ? W2 : W3;
    unsigned short* T = (z == 0) ? T0 : (z == 1) ? T1 : (z == 2) ? T2 : T3;
    __shared__ float t[64][65];
    const int k0 = blockIdx.y * 64, n0 = blockIdx.x * 64;
    const int row = threadIdx.x >> 6, col = threadIdx.x & 63;
#pragma unroll
    for (int p = 0; p < 16; ++p)
        t[p * 4 + row][col] = W[(size_t)(k0 + p * 4 + row) * Dm + n0 + col];
    __syncthreads();
#pragma unroll
    for (int p = 0; p < 16; ++p)
        T[(size_t)(n0 + p * 4 + row) * Dm + k0 + col] = f2bf(t[col][p * 4 + row]);
}

// ---------------- m97-style bf16 MFMA GEMM mainloop --------------------------
// C[128x128] tile at (m0,n0). A[M][K] bf16 row-major, Bt[N][K] bf16 (B^T).
// 4 waves, each 64x64 quadrant = 4x4 C-frags of 16x16x32 MFMA.
__device__ __forceinline__ void gemm128_mainloop(const unsigned short* __restrict__ A,
                                                 const unsigned short* __restrict__ Bt,
                                                 int K, int m0, int n0,
                                                 unsigned short* As, unsigned short* Bs,
                                                 floatx4 acc[4][4]) {
    const int tid = threadIdx.x;
    const int lane = tid & 63, wave = tid >> 6;
    const int l15 = lane & 15, quad = lane >> 4;
    const int wm = (wave >> 1) * 64, wn = (wave & 1) * 64;

    for (int k0 = 0; k0 < K; k0 += 32) {
        __syncthreads();
#pragma unroll
        for (int c = 0; c < 2; ++c) {
            const int idx = c * 256 + tid;
            const int row = idx >> 2, kc = (idx & 3) * 8;
            lds16(&As[row * 32 + kc], A + (size_t)(m0 + row) * K + k0 + kc);
            lds16(&Bs[row * 32 + kc], Bt + (size_t)(n0 + row) * K + k0 + kc);
        }
        __syncthreads();
        bf16x8 af[4], bf[4];
#pragma unroll
        for (int i = 0; i < 4; ++i)
            af[i] = *(const bf16x8*)&As[(wm + i * 16 + l15) * 32 + quad * 8];
#pragma unroll
        for (int j = 0; j < 4; ++j)
            bf[j] = *(const bf16x8*)&Bs[(wn + j * 16 + l15) * 32 + quad * 8];
#pragma unroll
        for (int i = 0; i < 4; ++i)
#pragma unroll
            for (int j = 0; j < 4; ++j)
                acc[i][j] = __builtin_amdgcn_mfma_f32_16x16x32_bf16(af[i], bf[j], acc[i][j], 0, 0, 0);
    }
}

// QKV fused: z selects weight/output. bf16 output with per-z scale.
__global__ __launch_bounds__(256) void gemm_qkv(const unsigned short* __restrict__ xb,
                                                const unsigned short* __restrict__ Wqt,
                                                const unsigned short* __restrict__ Wkt,
                                                const unsigned short* __restrict__ Wvt,
                                                unsigned short* __restrict__ Qb,
                                                unsigned short* __restrict__ Kb,
                                                unsigned short* __restrict__ Vb) {
    __shared__ unsigned short As[128 * 32];
    __shared__ unsigned short Bs[128 * 32];
    const int z = blockIdx.z;
    const unsigned short* Bt = (z == 0) ? Wqt : (z == 1) ? Wkt : Wvt;
    unsigned short* C = (z == 0) ? Qb : (z == 1) ? Kb : Vb;
    const float scale = (z == 0) ? 0.125f : 1.0f;
    const int m0 = blockIdx.y * 128, n0 = blockIdx.x * 128;

    floatx4 acc[4][4];
#pragma unroll
    for (int i = 0; i < 4; ++i)
#pragma unroll
        for (int j = 0; j < 4; ++j) acc[i][j] = (floatx4){0.f, 0.f, 0.f, 0.f};

    gemm128_mainloop(xb, Bt, Dm, m0, n0, As, Bs, acc);

    const int lane = threadIdx.x & 63, wave = threadIdx.x >> 6;
    const int l15 = lane & 15, quad = lane >> 4;
    const int wm = (wave >> 1) * 64, wn = (wave & 1) * 64;
#pragma unroll
    for (int i = 0; i < 4; ++i)
#pragma unroll
        for (int j = 0; j < 4; ++j)
#pragma unroll
            for (int r = 0; r < 4; ++r) {
                const int row = m0 + wm + i * 16 + quad * 4 + r;
                const int col = n0 + wn + j * 16 + l15;
                C[(size_t)row * Dm + col] = f2bf(acc[i][j][r] * scale);
            }
}

// Final GEMM: Yb @ Wo -> fp32 out.
__global__ __launch_bounds__(256) void gemm_out(const unsigned short* __restrict__ Yb,
                                                const unsigned short* __restrict__ Wot,
                                                float* __restrict__ out) {
    __shared__ unsigned short As[128 * 32];
    __shared__ unsigned short Bs[128 * 32];
    const int m0 = blockIdx.y * 128, n0 = blockIdx.x * 128;

    floatx4 acc[4][4];
#pragma unroll
    for (int i = 0; i < 4; ++i)
#pragma unroll
        for (int j = 0; j < 4; ++j) acc[i][j] = (floatx4){0.f, 0.f, 0.f, 0.f};

    gemm128_mainloop(Yb, Wot, Dm, m0, n0, As, Bs, acc);

    const int lane = threadIdx.x & 63, wave = threadIdx.x >> 6;
    const int l15 = lane & 15, quad = lane >> 4;
    const int wm = (wave >> 1) * 64, wn = (wave & 1) * 64;
#pragma unroll
    for (int i = 0; i < 4; ++i)
#pragma unroll
        for (int j = 0; j < 4; ++j)
#pragma unroll
            for (int r = 0; r < 4; ++r) {
                const int row = m0 + wm + i * 16 + quad * 4 + r;
                const int col = n0 + wn + j * 16 + l15;
                out[(size_t)row * Dm + col] = acc[i][j][r];
            }
}

// ---------------- V bf16 [tok][Dm] -> VbT bf16 [bh][d][T] --------------------
__global__ __launch_bounds__(256) void vtrans_b(const unsigned short* __restrict__ Vb,
                                                unsigned short* __restrict__ VbT) {
    __shared__ unsigned short tile[64][72];
    const int tt = blockIdx.x;   // 64-token tile
    const int h = blockIdx.y;
    const int row = threadIdx.x >> 6, col = threadIdx.x & 63;
#pragma unroll
    for (int p = 0; p < 16; ++p)
        tile[p * 4 + row][col] = Vb[(size_t)(tt * 64 + p * 4 + row) * Dm + h * HD + col];
    __syncthreads();
    const int gt0 = tt * 64;
    const int b = gt0 / Tseq;
    const int lt0 = gt0 - b * Tseq;
#pragma unroll
    for (int p = 0; p < 16; ++p) {
        const int d = p * 4 + row;
        VbT[((size_t)(b * NH + h) * HD + d) * Tseq + lt0 + col] = tile[col][d];
    }
}

// ------------------------- bf16 MFMA causal flash attention -------------------
// grid (B*NH=32, 16). Block = 4 waves; q-tile pair {y, 31-y} (33 K-tiles each).
__global__ __launch_bounds__(256) void attn_mfma(const unsigned short* __restrict__ Qb,
                                                 const unsigned short* __restrict__ Kb,
                                                 const unsigned short* __restrict__ VbT,
                                                 unsigned short* __restrict__ Yb) {
    const int bh = blockIdx.x;
    const int b = bh >> 4;
    const int h = bh & 15;
    const int ypair = blockIdx.y;
    const int tid = threadIdx.x;
    const int wave = tid >> 6;
    const int lane = tid & 63;
    const int l15 = lane & 15;
    const int quad = lane >> 4;

    __shared__ unsigned short Ks[64][72];
    __shared__ unsigned short Vt[64][72];
    __shared__ unsigned short Ps[4][16][72];

    const size_t tok0 = (size_t)b * Tseq;
    const int colh = h * HD;
    const unsigned short* vbase = VbT + (size_t)bh * HD * Tseq;

    const int srow = tid >> 5;
    const int scol2 = tid & 31;

    for (int phase = 0; phase < 2; ++phase) {
        const int qt = (phase == 0) ? ypair : (31 - ypair);
        const int qrow = qt * 64 + wave * 16;

        const unsigned short* qptr = Qb + (tok0 + qrow + l15) * Dm + colh + quad * 8;
        const bf16x8 qf0 = *(const bf16x8*)(qptr);
        const bf16x8 qf1 = *(const bf16x8*)(qptr + 32);

        float m_r[4], l_r[4];
        floatx4 o_acc[4];
#pragma unroll
        for (int r = 0; r < 4; ++r) { m_r[r] = -3.0e38f; l_r[r] = 0.f; }
#pragma unroll
        for (int t = 0; t < 4; ++t) o_acc[t] = (floatx4){0.f, 0.f, 0.f, 0.f};

        for (int kt = 0; kt <= qt; ++kt) {
            const int k0 = kt * 64;
            __syncthreads();
#pragma unroll
            for (int p = 0; p < 8; ++p) {
                const int rr = p * 8 + srow;
                *(unsigned int*)&Ks[rr][scol2 * 2] =
                    *(const unsigned int*)(Kb + (tok0 + k0 + rr) * Dm + colh + scol2 * 2);
                *(unsigned int*)&Vt[rr][scol2 * 2] =
                    *(const unsigned int*)(vbase + (size_t)rr * Tseq + k0 + scol2 * 2);
            }
            __syncthreads();

            floatx4 s[4];
#pragma unroll
            for (int t = 0; t < 4; ++t) {
                floatx4 c = (floatx4){0.f, 0.f, 0.f, 0.f};
                const bf16x8 b0 = *(const bf16x8*)&Ks[t * 16 + l15][quad * 8];
                const bf16x8 b1 = *(const bf16x8*)&Ks[t * 16 + l15][32 + quad * 8];
                c = __builtin_amdgcn_mfma_f32_16x16x32_bf16(qf0, b0, c, 0, 0, 0);
                c = __builtin_amdgcn_mfma_f32_16x16x32_bf16(qf1, b1, c, 0, 0, 0);
                s[t] = c;
            }

            if (kt == qt) {
#pragma unroll
                for (int t = 0; t < 4; ++t)
#pragma unroll
                    for (int r = 0; r < 4; ++r) {
                        const int kl = t * 16 + l15;
                        const int ql = wave * 16 + quad * 4 + r;
                        if (kl > ql) s[t][r] = -3.0e38f;
                    }
            }

            float rm[4];
#pragma unroll
            for (int r = 0; r < 4; ++r)
                rm[r] = fmaxf(fmaxf(s[0][r], s[1][r]), fmaxf(s[2][r], s[3][r]));
#pragma unroll
            for (int off = 1; off < 16; off <<= 1)
#pragma unroll
                for (int r = 0; r < 4; ++r)
                    rm[r] = fmaxf(rm[r], __shfl_xor(rm[r], off));
            float alpha[4];
#pragma unroll
            for (int r = 0; r < 4; ++r) {
                const float mn = fmaxf(m_r[r], rm[r]);
                alpha[r] = __expf(m_r[r] - mn);
                m_r[r] = mn;
            }
            float rs[4] = {0.f, 0.f, 0.f, 0.f};
#pragma unroll
            for (int t = 0; t < 4; ++t)
#pragma unroll
                for (int r = 0; r < 4; ++r) {
                    const float p = __expf(s[t][r] - m_r[r]);
                    rs[r] += p;
                    Ps[wave][quad * 4 + r][t * 16 + l15] = f2bf(p);
                }
#pragma unroll
            for (int off = 1; off < 16; off <<= 1)
#pragma unroll
                for (int r = 0; r < 4; ++r)
                    rs[r] += __shfl_xor(rs[r], off);
#pragma unroll
            for (int r = 0; r < 4; ++r)
                l_r[r] = l_r[r] * alpha[r] + rs[r];
#pragma unroll
            for (int t = 0; t < 4; ++t)
#pragma unroll
                for (int r = 0; r < 4; ++r)
                    o_acc[t][r] *= alpha[r];

            const bf16x8 pa0 = *(const bf16x8*)&Ps[wave][l15][quad * 8];
            const bf16x8 pa1 = *(const bf16x8*)&Ps[wave][l15][32 + quad * 8];
#pragma unroll
            for (int t = 0; t < 4; ++t) {
                const bf16x8 vb0 = *(const bf16x8*)&Vt[t * 16 + l15][quad * 8];
                const bf16x8 vb1 = *(const bf16x8*)&Vt[t * 16 + l15][32 + quad * 8];
                o_acc[t] = __builtin_amdgcn_mfma_f32_16x16x32_bf16(pa0, vb0, o_acc[t], 0, 0, 0);
                o_acc[t] = __builtin_amdgcn_mfma_f32_16x16x32_bf16(pa1, vb1, o_acc[t], 0, 0, 0);
            }
        }

#pragma unroll
        for (int t = 0; t < 4; ++t)
#pragma unroll
            for (int r = 0; r < 4; ++r) {
                const int q = qrow + quad * 4 + r;
                Yb[(tok0 + q) * Dm + colh + t * 16 + l15] = f2bf(o_acc[t][r] / l_r[r]);
            }
    }
}

// ------------------------------- launch --------------------------------------
extern "C" void kernel_launch(void* const* d_in, const int* in_sizes, int n_in,
                              void* d_out, int out_size, void* d_ws, size_t ws_size,
                              hipStream_t stream) {
    const float* x  = (const float*)d_in[0];
    const float* Wq = (const float*)d_in[1];
    const float* Wk = (const float*)d_in[2];
    const float* Wv = (const float*)d_in[3];
    const float* Wo = (const float*)d_in[4];
    float* out = (float*)d_out;

    const int M = Bsz * Tseq;  // 4096
    char* ws = (char*)d_ws;
    unsigned short* xb  = (unsigned short*)(ws);
    unsigned short* Wqt = (unsigned short*)(ws + (((size_t)8)  << 20));
    unsigned short* Wkt = (unsigned short*)(ws + (((size_t)10) << 20));
    unsigned short* Wvt = (unsigned short*)(ws + (((size_t)12) << 20));
    unsigned short* Wot = (unsigned short*)(ws + (((size_t)14) << 20));
    unsigned short* Qb  = (unsigned short*)(ws + (((size_t)16) << 20));
    unsigned short* Kb  = (unsigned short*)(ws + (((size_t)24) << 20));
    unsigned short* Vb  = (unsigned short*)(ws + (((size_t)32) << 20));
    unsigned short* VbT = (unsigned short*)(ws + (((size_t)40) << 20));
    unsigned short* Yb  = (unsigned short*)(ws + (((size_t)48) << 20));

    dim3 blk(256);
    hipLaunchKernelGGL(cast_x, dim3((M * Dm) / (4 * 256)), blk, 0, stream, x, xb);
    hipLaunchKernelGGL(wtrans, dim3(16, 16, 4), blk, 0, stream,
                       Wq, Wk, Wv, Wo, Wqt, Wkt, Wvt, Wot);

    hipLaunchKernelGGL(gemm_qkv, dim3(Dm / 128, M / 128, 3), blk, 0, stream,
                       xb, Wqt, Wkt, Wvt, Qb, Kb, Vb);

    hipLaunchKernelGGL(vtrans_b, dim3(M / 64, NH), blk, 0, stream, Vb, VbT);

    hipLaunchKernelGGL(attn_mfma, dim3(Bsz * NH, 16), blk, 0, stream, Qb, Kb, VbT, Yb);

    hipLaunchKernelGGL(gemm_out, dim3(Dm / 128, M / 128), blk, 0, stream, Yb, Wot, out);
}